// Round 8
// baseline (593.759 us; speedup 1.0000x reference)
//
#include <hip/hip_runtime.h>
#include <hip/hip_bf16.h>
#include <math.h>

#define NT 512   // 8 waves
#define EB 16    // edges per block (2 per wave in phase 1)

using sv4    = __attribute__((ext_vector_type(4))) short;
using short8 = __attribute__((ext_vector_type(8))) short;
using f32x4  = __attribute__((ext_vector_type(4))) float;
typedef unsigned short u16;

#define MFMA(a,b,c) __builtin_amdgcn_mfma_f32_16x16x32_bf16((a),(b),(c),0,0,0)

// ---- swizzled-weight fragment table (each frag = 64 lanes x 8 bf16 = 1024B)
#define FW0   0     // so2_w0: K=464->480 (15 kt) x N=160 (10 nt) = 150 frags
#define FW1R  150   // w1r: K=144->160 (5) x N=48 (3) = 15
#define FW1I  165
#define FW1IN 180   // -w1i
#define FW2R  195   // w2r: K=48->64 (2) x N=16 (1) = 2
#define FW2I  197
#define FW2IN 199
#define FL0   201   // lp_w0: K=64 (2) x N=64 (4) = 8
#define FL1   209   // lp_w1: K=32 (1) x N=32 (2) = 2
#define FL2   211   // lp_w2: K=16->32 (1) x N=16 (1) = 1
#define NFRAG 212
#define WS_NLS_OFF (NFRAG * 512)   // u16 elements offset of node-LN table in ws

__device__ __forceinline__ u16 f2b(float x) {
  __hip_bfloat16 h = __float2bfloat16(x);
  return *reinterpret_cast<u16*>(&h);
}
__device__ __forceinline__ float b2f(u16 u) {
  __hip_bfloat16 h; *reinterpret_cast<u16*>(&h) = u;
  return __bfloat162float(h);
}
__device__ __forceinline__ sv4    ld4(const u16* p){ return *reinterpret_cast<const sv4*>(p); }
__device__ __forceinline__ short8 ld8(const u16* p){ return *reinterpret_cast<const short8*>(p); }

// ---------------- weight pre-swizzle: f32 [K][N] -> bf16 B-fragments ----------
__global__ void prep_w(const float* __restrict__ w0,
                       const float* __restrict__ w1r, const float* __restrict__ w1i,
                       const float* __restrict__ w2r, const float* __restrict__ w2i,
                       const float* __restrict__ l0,  const float* __restrict__ l1,
                       const float* __restrict__ l2,  u16* __restrict__ ws) {
  const int g = blockIdx.x * 256 + threadIdx.x;
  if (g >= NFRAG * 64) return;
  const int frag = g >> 6, lane = g & 63;
  const float* src; int K, N, kt, nt; float sgn = 1.f;
  if (frag < FW1R)       { src = w0;  K = 464; N = 160; int f = frag;       kt = f/10; nt = f%10; }
  else if (frag < FW1I)  { src = w1r; K = 144; N = 48;  int f = frag-FW1R;  kt = f/3;  nt = f%3; }
  else if (frag < FW1IN) { src = w1i; K = 144; N = 48;  int f = frag-FW1I;  kt = f/3;  nt = f%3; }
  else if (frag < FW2R)  { src = w1i; K = 144; N = 48;  int f = frag-FW1IN; kt = f/3;  nt = f%3; sgn = -1.f; }
  else if (frag < FW2I)  { src = w2r; K = 48;  N = 16;  kt = frag-FW2R; nt = 0; }
  else if (frag < FW2IN) { src = w2i; K = 48;  N = 16;  kt = frag-FW2I; nt = 0; }
  else if (frag < FL0)   { src = w2i; K = 48;  N = 16;  kt = frag-FW2IN; nt = 0; sgn = -1.f; }
  else if (frag < FL1)   { src = l0;  K = 64;  N = 64;  int f = frag-FL0;   kt = f/4;  nt = f%4; }
  else if (frag < FL2)   { src = l1;  K = 32;  N = 32;  kt = 0; nt = frag-FL1; }
  else                   { src = l2;  K = 16;  N = 16;  kt = 0; nt = 0; }
  const int n  = nt*16 + (lane & 15);
  const int k0 = kt*32 + (lane >> 4) * 8;
  u16* dst = ws + (size_t)frag * 512 + lane * 8;
  #pragma unroll
  for (int j = 0; j < 8; ++j) {
    const int k = k0 + j;
    const float v = (k < K && n < N) ? src[k * N + n] * sgn : 0.f;
    dst[j] = f2b(v);
  }
}

// ---------------- node pre-LN: f32[N][240] -> packed bf16[N][320] -------------
__global__ void ln_nodes(const float* __restrict__ nodef,
                         const float* __restrict__ w0, const float* __restrict__ b0,
                         const float* __restrict__ w1, const float* __restrict__ w2,
                         u16* __restrict__ nls, int N) {
  const int row  = blockIdx.x * 4 + (threadIdx.x >> 6);
  const int lane = threadIdx.x & 63;
  if (row >= N) return;
  const float* src = nodef + (size_t)row * 240;
  const float v0 = src[lane];
  const float v1 = src[lane + 64];
  const float v2 = src[lane + 128];
  const float v3 = (lane < 48) ? src[lane + 192] : 0.f;
  const bool lo = (lane < 32);
  float sm = v0, sq = v0*v0;
  float S1 = v1*v1 + (lo ? v2*v2 : 0.f);
  float S2 = (lo ? 0.f : v2*v2) + v3*v3;
  #pragma unroll
  for (int s = 32; s > 0; s >>= 1) {
    sm += __shfl_xor(sm, s, 64); sq += __shfl_xor(sq, s, 64);
    S1 += __shfl_xor(S1, s, 64); S2 += __shfl_xor(S2, s, 64);
  }
  const float mu  = sm * (1.f/64.f);
  const float i0  = rsqrtf(sq*(1.f/64.f) - mu*mu + 1e-8f);
  const float inv = rsqrtf(0.5f*(S1*(1.f/96.f) + S2*(1.f/80.f)) + 1e-8f);
  u16* dst = nls + (size_t)row * 320;
  dst[lane] = f2b((v0 - mu) * i0 * w0[lane] + b0[lane]);
  { const int u = lane;      const int c = u/3, j = u-3*c; dst[64 + 4*c + j]  = f2b(v1*inv*w1[c]); }
  if (lo) { const int u = lane+64; const int c = u/3, j = u-3*c; dst[64 + 4*c + j]  = f2b(v2*inv*w1[c]); }
  else    { const int u = lane-32; const int c = u/5, j = u-5*c; dst[192 + 8*c + j] = f2b(v2*inv*w2[c]); }
  if (lane < 48) { const int u = lane+32; const int c = u/5, j = u-5*c; dst[192 + 8*c + j] = f2b(v3*inv*w2[c]); }
  if (lane < 32) dst[64 + 4*lane + 3] = 0;
  if (lane < 48) { const int c = lane/3, j = lane-3*c; dst[192 + 8*c + 5 + j] = 0; }
}

// ------------------------------ main fused kernel -----------------------------
// LDS layout (bytes), total 40608 -> 4 blocks/CU (8 waves each = 32 waves/CU):
//  0     m0  u16[16 x 472 +8]    | alias: o0f f32[16][164] @0 ; g1s 3x[16x40]u16 @10496
//  15120 p1  u16[16 x 152 +8]    | alias: op1f f32[16][52]
//  20000 n1  u16[16 x 152 +8]    | alias: on1f f32[16][52]
//  24880 p2  u16[16 x 56 +8]     | alias: op2f f32[16][20]
//  26688 n2  u16[16 x 56 +8]     | alias: on2f f32[16][20]
//  28496 scr8 f32[8][176]        | alias: gates u16[16][48] @28496 ; scs u16[16x72] @30032
//  34128 Dc  f32[16][40]
//  36688 g2s 5 x u16[16x24 +8]   (ends 40608)
__global__ __launch_bounds__(NT, 6)
void iel_mfma(const float* __restrict__ latents,
              const float* __restrict__ edgef,
              const float* __restrict__ wig,
              const float* __restrict__ ln_e_w0, const float* __restrict__ ln_e_b0,
              const float* __restrict__ ln_e_w1, const float* __restrict__ ln_e_w2,
              const float* __restrict__ lp_b0,
              const int* __restrict__ edge_index, const int* __restrict__ active_edges,
              const u16* __restrict__ ws, const u16* __restrict__ nls,
              float* __restrict__ out,
              int Etot, int A)
{
  __shared__ __align__(16) char SMEM[40608];
  u16*   m0   = (u16*)(SMEM);
  u16*   p1   = (u16*)(SMEM + 15120);
  u16*   n1   = (u16*)(SMEM + 20000);
  u16*   p2   = (u16*)(SMEM + 24880);
  u16*   n2   = (u16*)(SMEM + 26688);
  float* scr8 = (float*)(SMEM + 28496);
  float* Dc   = (float*)(SMEM + 34128);
  u16*   g2s  = (u16*)(SMEM + 36688);
  float* o0f  = (float*)(SMEM);
  u16*   g1s  = (u16*)(SMEM + 10496);
  float* op1f = (float*)(SMEM + 15120);
  float* on1f = (float*)(SMEM + 20000);
  float* op2f = (float*)(SMEM + 24880);
  float* on2f = (float*)(SMEM + 26688);
  u16*   gates= (u16*)(SMEM + 28496);
  u16*   scs  = (u16*)(SMEM + 30032);

  const short8* WF = (const short8*)ws;
  const int t    = threadIdx.x;
  const int lane = t & 63;
  const int w    = t >> 6;           // 0..7
  const int eb0  = blockIdx.x * EB;
  const f32x4 Z4 = {0.f, 0.f, 0.f, 0.f};

  // ---- pad/tail clear (threads 0..255): MFMA A-operands must be NaN-free ----
  if (t < 256) {
    const int r = t >> 4, c = t & 15;
    if (c < 8) {
      m0[r*472 + 464 + c] = 0;
      p1[r*152 + 144 + c] = 0;
      n1[r*152 + 144 + c] = 0;
      p2[r*56  + 48  + c] = 0;
      n2[r*56  + 48  + c] = 0;
      #pragma unroll
      for (int m = 0; m < 5; ++m) g2s[m*392 + r*24 + 16 + c] = 0;
    }
    if (t < 8) {
      m0[16*472 + t] = 0;
      p1[16*152 + t] = 0;
      n1[16*152 + t] = 0;
      p2[16*56  + t] = 0;
      n2[16*56  + t] = 0;
      #pragma unroll
      for (int m = 0; m < 5; ++m) g2s[m*392 + 384 + t] = 0;
    }
  }

  // ---- per-lane rotation invariants ----
  const int c1 = lane / 3, i1 = lane - c1*3;
  const bool q2lo = (lane < 32);
  const int u2 = q2lo ? lane + 64 : lane - 32;
  const int c2 = q2lo ? u2/3 : u2/5;
  const int i2 = q2lo ? (u2 - c2*3) : (u2 - c2*5);
  const int u3 = (lane < 48) ? lane + 32 : 79;
  const int c3 = u3/5, i3 = u3 - c3*5;

  // ---- hoisted edge-LN weights ----
  const float w0e = ln_e_w0[lane], b0e = ln_e_b0[lane];
  const float wAe = ln_e_w1[c1];
  const float wBe = q2lo ? ln_e_w1[c2] : ln_e_w2[c2];
  const float wCe = ln_e_w2[c3];

  float* swr = scr8 + w * 176;

  // ---- edge index prefetch (wave's 2 edges) ----
  int aev[2], ecv[2], env[2];
  #pragma unroll
  for (int it = 0; it < 2; ++it) {
    const int e = eb0 + (w<<1) + it;
    aev[it] = active_edges[(e < A) ? e : (A-1)];
  }
  #pragma unroll
  for (int it = 0; it < 2; ++it) {
    ecv[it] = edge_index[aev[it]];
    env[it] = edge_index[Etot + aev[it]];
  }

  // ---- stage compact Wigner D for this wave's 2 edges ----
  #pragma unroll
  for (int it = 0; it < 2; ++it) {
    const int el = (w<<1) + it;
    const int e  = eb0 + el;
    const int eS = (e < A) ? e : (A-1);
    if (lane < 35) {
      int src, dst;
      if (lane == 0)      { src = 0; dst = 0; }
      else if (lane < 10) { const int a=(lane-1)/3, b=(lane-1)-3*((lane-1)/3); src=(1+a)*9+(1+b); dst=lane; }
      else                { const int a=(lane-10)/5, b=(lane-10)-5*((lane-10)/5); src=(4+a)*9+(4+b); dst=lane+2; }
      Dc[el*40 + dst] = wig[(size_t)eS*81 + src];
    }
  }

  struct ER {
    u16 q0a, q0b;
    sv4 t1a, t1b, t2aa, t2ab;
    short8 t2ba, t2bb, t3a, t3b;
    float e0, e1, e2, e3, l0, l1;
  };
  ER RA, RB;

  auto issue = [&](int it, ER& R) {
    const int e  = eb0 + (w<<1) + it;
    const int eS = (e < A) ? e : (A-1);
    const u16* nba = nls + (size_t)ecv[it]*320;
    const u16* nbb = nls + (size_t)env[it]*320;
    R.q0a = nba[lane];              R.q0b = nbb[lane];
    R.t1a = ld4(nba + 64 + 4*c1);   R.t1b = ld4(nbb + 64 + 4*c1);
    if (q2lo) { R.t2aa = ld4(nba + 64 + 4*c2);  R.t2ab = ld4(nbb + 64 + 4*c2); }
    else      { R.t2ba = ld8(nba + 192 + 8*c2); R.t2bb = ld8(nbb + 192 + 8*c2); }
    if (lane < 48) { R.t3a = ld8(nba + 192 + 8*c3); R.t3b = ld8(nbb + 192 + 8*c3); }
    const float* ep = edgef + (size_t)eS*240;
    R.e0 = ep[lane]; R.e1 = ep[lane+64]; R.e2 = ep[lane+128];
    R.e3 = (lane < 48) ? ep[lane+192] : 0.f;
    const float* lr = latents + (size_t)aev[it]*128;
    R.l0 = lr[lane]; R.l1 = lr[64+lane];
  };

  auto nodeWrite = [&](int el, int r, u16 q0, sv4 t1, sv4 t2a, short8 t2b, short8 t3,
                       float d00, const float* d1v, const float* d2v, const float* d3v) {
    const int mb = el*472 + r*112;
    m0[mb + lane] = f2b(b2f(q0) * d00);
    {
      const float v = d1v[0]*b2f((u16)t1[0]) + d1v[1]*b2f((u16)t1[1]) + d1v[2]*b2f((u16)t1[2]);
      const u16 bv = f2b(v);
      if (i1 == 1)      m0[mb + 64 + c1] = bv;
      else if (i1 == 2) p1[el*152 + r*48 + c1] = bv;
      else              n1[el*152 + r*48 + c1] = bv;
    }
    if (q2lo) {
      const float v = d2v[0]*b2f((u16)t2a[0]) + d2v[1]*b2f((u16)t2a[1]) + d2v[2]*b2f((u16)t2a[2]);
      const u16 bv = f2b(v);
      if (i2 == 1)      m0[mb + 64 + c2] = bv;
      else if (i2 == 2) p1[el*152 + r*48 + c2] = bv;
      else              n1[el*152 + r*48 + c2] = bv;
    } else {
      float v = 0.f;
      #pragma unroll
      for (int j = 0; j < 5; ++j) v += d2v[j]*b2f((u16)t2b[j]);
      const u16 bv = f2b(v);
      if (i2 == 2)      m0[mb + 96 + c2] = bv;
      else if (i2 == 3) p1[el*152 + r*48 + 32 + c2] = bv;
      else if (i2 == 1) n1[el*152 + r*48 + 32 + c2] = bv;
      else if (i2 == 4) p2[el*56 + r*16 + c2] = bv;
      else              n2[el*56 + r*16 + c2] = bv;
    }
    if (lane < 48) {
      float v = 0.f;
      #pragma unroll
      for (int j = 0; j < 5; ++j) v += d3v[j]*b2f((u16)t3[j]);
      const u16 bv = f2b(v);
      if (i3 == 2)      m0[mb + 96 + c3] = bv;
      else if (i3 == 3) p1[el*152 + r*48 + 32 + c3] = bv;
      else if (i3 == 1) n1[el*152 + r*48 + 32 + c3] = bv;
      else if (i3 == 4) p2[el*56 + r*16 + c3] = bv;
      else              n2[el*56 + r*16 + c3] = bv;
    }
  };

  auto process = [&](int it, ER& R) {
    const int el = (w<<1) + it;
    const float* DcE = Dc + el*40;
    const float d00 = DcE[0];
    float d1v[3], d2v[5], d3v[5];
    #pragma unroll
    for (int j = 0; j < 3; ++j) d1v[j] = DcE[1 + i1*3 + j];
    #pragma unroll
    for (int j = 0; j < 5; ++j) d2v[j] = q2lo ? ((j < 3) ? DcE[1 + i2*3 + j] : 0.f)
                                              : DcE[12 + i2*5 + j];
    #pragma unroll
    for (int j = 0; j < 5; ++j) d3v[j] = DcE[12 + i3*5 + j];

    nodeWrite(el, 0, R.q0a, R.t1a, R.t2aa, R.t2ba, R.t3a, d00, d1v, d2v, d3v);
    nodeWrite(el, 2, R.q0b, R.t1b, R.t2ab, R.t2bb, R.t3b, d00, d1v, d2v, d3v);

    // edge row (r=1): full LN
    {
      const float v0 = R.e0, v1 = R.e1, v2 = R.e2, v3 = R.e3;
      float sm = v0, sq = v0*v0;
      float S1 = v1*v1 + (q2lo ? v2*v2 : 0.f);
      float S2 = (q2lo ? 0.f : v2*v2) + v3*v3;
      #pragma unroll
      for (int s = 32; s > 0; s >>= 1) {
        sm += __shfl_xor(sm, s, 64); sq += __shfl_xor(sq, s, 64);
        S1 += __shfl_xor(S1, s, 64); S2 += __shfl_xor(S2, s, 64);
      }
      const float mu = sm * (1.f/64.f);
      const float i0 = rsqrtf(sq*(1.f/64.f) - mu*mu + 1e-8f);
      const float iv = rsqrtf(0.5f*(S1*(1.f/96.f) + S2*(1.f/80.f)) + 1e-8f);
      swr[lane]       = v1 * iv * wAe;
      swr[64 + lane]  = v2 * iv * wBe;
      if (lane < 48) swr[128 + lane] = v3 * iv * wCe;
      asm volatile("s_waitcnt lgkmcnt(0)" ::: "memory");
      const int mb = el*472 + 112;
      m0[mb + lane] = f2b(((v0 - mu)*i0*w0e + b0e) * d00);
      {
        const float* sb = swr + 3*c1;
        const float v = d1v[0]*sb[0] + d1v[1]*sb[1] + d1v[2]*sb[2];
        const u16 bv = f2b(v);
        if (i1 == 1)      m0[mb + 64 + c1] = bv;
        else if (i1 == 2) p1[el*152 + 48 + c1] = bv;
        else              n1[el*152 + 48 + c1] = bv;
      }
      if (q2lo) {
        const float* sb = swr + 3*c2;
        const float v = d2v[0]*sb[0] + d2v[1]*sb[1] + d2v[2]*sb[2];
        const u16 bv = f2b(v);
        if (i2 == 1)      m0[mb + 64 + c2] = bv;
        else if (i2 == 2) p1[el*152 + 48 + c2] = bv;
        else              n1[el*152 + 48 + c2] = bv;
      } else {
        const float* sb = swr + 96 + 5*c2;
        float v = 0.f;
        #pragma unroll
        for (int j = 0; j < 5; ++j) v += d2v[j]*sb[j];
        const u16 bv = f2b(v);
        if (i2 == 2)      m0[mb + 96 + c2] = bv;
        else if (i2 == 3) p1[el*152 + 48 + 32 + c2] = bv;
        else if (i2 == 1) n1[el*152 + 48 + 32 + c2] = bv;
        else if (i2 == 4) p2[el*56 + 16 + c2] = bv;
        else              n2[el*56 + 16 + c2] = bv;
      }
      if (lane < 48) {
        const float* sb = swr + 96 + 5*c3;
        float v = 0.f;
        #pragma unroll
        for (int j = 0; j < 5; ++j) v += d3v[j]*sb[j];
        const u16 bv = f2b(v);
        if (i3 == 2)      m0[mb + 96 + c3] = bv;
        else if (i3 == 3) p1[el*152 + 48 + 32 + c3] = bv;
        else if (i3 == 1) n1[el*152 + 48 + 32 + c3] = bv;
        else if (i3 == 4) p2[el*56 + 16 + c3] = bv;
        else              n2[el*56 + 16 + c3] = bv;
      }
    }
    m0[el*472 + 336 + lane] = f2b(R.l0);
    m0[el*472 + 400 + lane] = f2b(R.l1);
  };

  // ---- Phase 1 (2 edges per wave, loads双-buffered) ----
  issue(0, RA);
  issue(1, RB);
  process(0, RA);
  process(1, RB);
  __syncthreads();  // B2: features + Dc ready

  // ---- Phase 2a: o0 = m0 @ so2_w0 (10 N-tiles over 8 waves) ----
  f32x4 acc2a[2] = {Z4, Z4};
  {
    const u16* abase = m0 + (lane & 15)*472 + (lane >> 4)*8;
    #pragma unroll
    for (int kt = 0; kt < 15; ++kt) {
      const short8 a = *reinterpret_cast<const short8*>(abase + kt*32);
      #pragma unroll
      for (int i = 0; i < 2; ++i) {
        const int nt = w + 8*i;
        if (nt < 10)
          acc2a[i] = MFMA(a, WF[(size_t)(FW0 + kt*10 + nt)*64 + lane], acc2a[i]);
      }
    }
  }
  // ---- Phase 2b (waves 0-5) / 2c (waves 6-7) ----
  f32x4 acc2b = Z4;
  f32x4 acc2c = Z4;
  if (w < 6) {
    const u16* pbase = p1 + (lane & 15)*152 + (lane >> 4)*8;
    const u16* nbase = n1 + (lane & 15)*152 + (lane >> 4)*8;
    const int isOn = (w >= 3) ? 1 : 0;
    const int nt2 = w - 3*isOn;
    #pragma unroll
    for (int kt = 0; kt < 5; ++kt) {
      const short8 pa = *reinterpret_cast<const short8*>(pbase + kt*32);
      const short8 na = *reinterpret_cast<const short8*>(nbase + kt*32);
      acc2b = MFMA(pa, WF[(size_t)((isOn?FW1I:FW1R)  + kt*3 + nt2)*64 + lane], acc2b);
      acc2b = MFMA(na, WF[(size_t)((isOn?FW1R:FW1IN) + kt*3 + nt2)*64 + lane], acc2b);
    }
  } else {
    const u16* pb2 = p2 + (lane & 15)*56 + (lane >> 4)*8;
    const u16* nb2 = n2 + (lane & 15)*56 + (lane >> 4)*8;
    const int isOn2 = (w == 7);
    #pragma unroll
    for (int kt = 0; kt < 2; ++kt) {
      const short8 pa = *reinterpret_cast<const short8*>(pb2 + kt*32);
      const short8 na = *reinterpret_cast<const short8*>(nb2 + kt*32);
      acc2c = MFMA(pa, WF[(size_t)((isOn2?FW2I:FW2R)  + kt)*64 + lane], acc2c);
      acc2c = MFMA(na, WF[(size_t)((isOn2?FW2R:FW2IN) + kt)*64 + lane], acc2c);
    }
  }
  __syncthreads();  // B3: all feature reads done

  // o0 write (aliases m0)
  {
    #pragma unroll
    for (int i = 0; i < 2; ++i) {
      const int nt = w + 8*i;
      if (nt < 10) {
        const int col = nt*16 + (lane & 15);
        const int r0  = (lane >> 4)*4;
        #pragma unroll
        for (int j = 0; j < 4; ++j)
          o0f[(r0+j)*164 + col] = acc2a[i][j] * 0.046423835f;   // 1/sqrt(464)
      }
    }
  }
  __syncthreads();  // B4: o0 ready

  // op1/on1/op2/on2 writes (alias p1/n1/p2/n2) + A1 (silu/gates, reads o0)
  {
    if (w < 6) {
      const int isOn = (w >= 3) ? 1 : 0;
      const int nt2 = w - 3*isOn;
      float* dst = isOn ? on1f : op1f;
      const int col = nt2*16 + (lane & 15);
      const int r0  = (lane >> 4)*4;
      #pragma unroll
      for (int j = 0; j < 4; ++j)
        dst[(r0+j)*52 + col] = acc2b[j] * (1.f/12.f);
    } else {
      float* dst = (w == 7) ? on2f : op2f;
      const int r0 = (lane >> 4)*4;
      #pragma unroll
      for (int j = 0; j < 4; ++j)
        dst[(r0+j)*20 + (lane & 15)] = acc2c[j] * 0.14433757f;  // 1/sqrt(48)
    }
  }
  {
    const int e = t >> 5, l32 = t & 31;
    const float d0 = Dc[e*40];
    #pragma unroll
    for (int k = 0; k < 4; ++k) {
      const int p = l32 + 32*k;
      if (p < 112) {
        const float x = o0f[e*164 + p] * d0;
        const float sg = 1.f/(1.f + __expf(-x));
        if (p < 64) scs[e*72 + p] = f2b(x * sg);
        else        gates[e*48 + (p - 64)] = f2b(sg);
      }
    }
  }
  __syncthreads();  // B5

  // A2: rotate-back + gate -> g1/g2 bf16 staging (D coefs from LDS)
  {
    const int e = t >> 5, l32 = t & 31;
    const float* DcE = Dc + e*40;
    #pragma unroll
    for (int k = 0; k < 3; ++k) {
      const int item = l32 + 32*k;            // 0..95
      const int c = item/3, m = item - 3*c;
      const float val = DcE[1 + m]     * on1f[e*52 + c]
                      + DcE[1 + 3 + m] * o0f[e*164 + 112 + c]
                      + DcE[1 + 6 + m] * op1f[e*52 + c];
      const float g = b2f(gates[e*48 + c]);
      g1s[m*640 + e*40 + c] = f2b(val * g);
    }
    if (l32 < 16) {
      const int c = l32;
      const float f0 = on2f[e*20 + c];
      const float f1 = on1f[e*52 + 32 + c];
      const float f2c = o0f[e*164 + 144 + c];
      const float f3 = op1f[e*52 + 32 + c];
      const float f4 = op2f[e*20 + c];
      const float gg = b2f(gates[e*48 + 32 + c]);
      #pragma unroll
      for (int m = 0; m < 5; ++m) {
        const float val = DcE[12 + m]*f0 + DcE[12 + 5 + m]*f1 + DcE[12 + 10 + m]*f2c
                        + DcE[12 + 15 + m]*f3 + DcE[12 + 20 + m]*f4;
        g2s[m*392 + e*24 + c] = f2b(val * gg);
      }
    }
  }
  __syncthreads();  // B6

  // ---- Phase 3: final small matmuls (15 MFMA tasks over 8 waves) + store ----
  for (int tau = w; tau < 15; tau += 8) {
    const int col16 = lane & 15;
    const int r0 = (lane >> 4)*4;
    if (tau < 4) {            // y0: sc[16x64] @ lp_w0
      const int ntt = tau;
      f32x4 a0 = Z4;
      #pragma unroll
      for (int kt = 0; kt < 2; ++kt) {
        const short8 a = *reinterpret_cast<const short8*>(
            scs + (lane & 15)*72 + kt*32 + (lane >> 4)*8);
        a0 = MFMA(a, WF[(size_t)(FL0 + kt*4 + ntt)*64 + lane], a0);
      }
      const int col = ntt*16 + col16;
      const float bias = lp_b0[col];
      #pragma unroll
      for (int j = 0; j < 4; ++j) {
        const int er = eb0 + r0 + j;
        if (er < A) out[(size_t)er*240 + col] = a0[j]*0.125f + bias;
      }
    } else if (tau < 10) {    // y1: g1[m][16x32] @ lp_w1
      const int u = tau - 4, m = u >> 1, ntt = u & 1;
      const short8 a = *reinterpret_cast<const short8*>(
          g1s + m*640 + (lane & 15)*40 + (lane >> 4)*8);
      f32x4 a0 = Z4;
      a0 = MFMA(a, WF[(size_t)(FL1 + ntt)*64 + lane], a0);
      const int d = ntt*16 + col16;
      const int col = 64 + d*3 + m;
      #pragma unroll
      for (int j = 0; j < 4; ++j) {
        const int er = eb0 + r0 + j;
        if (er < A) out[(size_t)er*240 + col] = a0[j]*0.17677670f;  // 1/sqrt(32)
      }
    } else {                  // y2: g2[m][16x32(zero-pad)] @ lp_w2
      const int m = tau - 10;
      const short8 a = *reinterpret_cast<const short8*>(
          g2s + m*392 + (lane & 15)*24 + (lane >> 4)*8);
      f32x4 a0 = Z4;
      a0 = MFMA(a, WF[(size_t)FL2*64 + lane], a0);
      const int col = 160 + col16*5 + m;
      #pragma unroll
      for (int j = 0; j < 4; ++j) {
        const int er = eb0 + r0 + j;
        if (er < A) out[(size_t)er*240 + col] = a0[j]*0.25f;        // 1/sqrt(16)
      }
    }
  }
}

extern "C" void kernel_launch(void* const* d_in, const int* in_sizes, int n_in,
                              void* d_out, int out_size, void* d_ws, size_t ws_size,
                              hipStream_t stream) {
  const float* latents  = (const float*)d_in[0];
  const float* nodef    = (const float*)d_in[1];
  const float* edgef    = (const float*)d_in[2];
  const float* wig      = (const float*)d_in[4];
  const float* ln_n_w0  = (const float*)d_in[5];
  const float* ln_n_b0  = (const float*)d_in[6];
  const float* ln_n_w1  = (const float*)d_in[7];
  const float* ln_n_w2  = (const float*)d_in[8];
  const float* ln_e_w0  = (const float*)d_in[9];
  const float* ln_e_b0  = (const float*)d_in[10];
  const float* ln_e_w1  = (const float*)d_in[11];
  const float* ln_e_w2  = (const float*)d_in[12];
  const float* so2_w0   = (const float*)d_in[13];
  const float* so2_w1r  = (const float*)d_in[14];
  const float* so2_w1i  = (const float*)d_in[15];
  const float* so2_w2r  = (const float*)d_in[16];
  const float* so2_w2i  = (const float*)d_in[17];
  const float* lp_w0    = (const float*)d_in[18];
  const float* lp_b0    = (const float*)d_in[19];
  const float* lp_w1    = (const float*)d_in[20];
  const float* lp_w2    = (const float*)d_in[21];
  const int*   edge_index   = (const int*)d_in[22];
  const int*   active_edges = (const int*)d_in[23];

  const int Etot = in_sizes[2] / 240;
  const int N    = in_sizes[1] / 240;
  const int A    = in_sizes[23];

  u16* ws  = (u16*)d_ws;                 // WF table: NFRAG*1024 B
  u16* nls = ws + WS_NLS_OFF;            // node-LN table: N*640 B

  const int pthreads = NFRAG * 64;
  hipLaunchKernelGGL(prep_w, dim3((pthreads + 255) / 256), dim3(256), 0, stream,
                     so2_w0, so2_w1r, so2_w1i, so2_w2r, so2_w2i,
                     lp_w0, lp_w1, lp_w2, ws);

  hipLaunchKernelGGL(ln_nodes, dim3((N + 3) / 4), dim3(256), 0, stream,
                     nodef, ln_n_w0, ln_n_b0, ln_n_w1, ln_n_w2, nls, N);

  const int grid = (A + EB - 1) / EB;
  hipLaunchKernelGGL(iel_mfma, dim3(grid), dim3(NT), 0, stream,
                     latents, edgef, wig,
                     ln_e_w0, ln_e_b0, ln_e_w1, ln_e_w2,
                     lp_b0, edge_index, active_edges, ws, nls,
                     (float*)d_out, Etot, A);
}

// Round 10
// 403.972 us; speedup vs baseline: 1.4698x; 1.4698x over previous
//
#include <hip/hip_runtime.h>
#include <hip/hip_bf16.h>
#include <math.h>

#define NT 256   // 4 waves
#define EB 16    // edges per block

using sv4    = __attribute__((ext_vector_type(4))) short;
using short8 = __attribute__((ext_vector_type(8))) short;
using f32x4  = __attribute__((ext_vector_type(4))) float;
typedef unsigned short u16;

#define MFMA(a,b,c) __builtin_amdgcn_mfma_f32_16x16x32_bf16((a),(b),(c),0,0,0)

// ---- swizzled-weight fragment table (each frag = 64 lanes x 8 bf16 = 1024B)
#define FW0   0
#define FW1R  150
#define FW1I  165
#define FW1IN 180
#define FW2R  195
#define FW2I  197
#define FW2IN 199
#define FL0   201
#define FL1   209
#define FL2   211
#define NFRAG 212
#define WS_NLS_OFF (NFRAG * 512)

__device__ __forceinline__ u16 f2b(float x) {
  __hip_bfloat16 h = __float2bfloat16(x);
  return *reinterpret_cast<u16*>(&h);
}
__device__ __forceinline__ float b2f(u16 u) {
  __hip_bfloat16 h; *reinterpret_cast<u16*>(&h) = u;
  return __bfloat162float(h);
}
__device__ __forceinline__ sv4 ld4(const u16* p){ return *reinterpret_cast<const sv4*>(p); }

// ---------------- weight pre-swizzle ------------------------------------------
__global__ void prep_w(const float* __restrict__ w0,
                       const float* __restrict__ w1r, const float* __restrict__ w1i,
                       const float* __restrict__ w2r, const float* __restrict__ w2i,
                       const float* __restrict__ l0,  const float* __restrict__ l1,
                       const float* __restrict__ l2,  u16* __restrict__ ws) {
  const int g = blockIdx.x * 256 + threadIdx.x;
  if (g >= NFRAG * 64) return;
  const int frag = g >> 6, lane = g & 63;
  const float* src; int K, N, kt, nt; float sgn = 1.f;
  if (frag < FW1R)       { src = w0;  K = 464; N = 160; int f = frag;       kt = f/10; nt = f%10; }
  else if (frag < FW1I)  { src = w1r; K = 144; N = 48;  int f = frag-FW1R;  kt = f/3;  nt = f%3; }
  else if (frag < FW1IN) { src = w1i; K = 144; N = 48;  int f = frag-FW1I;  kt = f/3;  nt = f%3; }
  else if (frag < FW2R)  { src = w1i; K = 144; N = 48;  int f = frag-FW1IN; kt = f/3;  nt = f%3; sgn = -1.f; }
  else if (frag < FW2I)  { src = w2r; K = 48;  N = 16;  kt = frag-FW2R; nt = 0; }
  else if (frag < FW2IN) { src = w2i; K = 48;  N = 16;  kt = frag-FW2I; nt = 0; }
  else if (frag < FL0)   { src = w2i; K = 48;  N = 16;  kt = frag-FW2IN; nt = 0; sgn = -1.f; }
  else if (frag < FL1)   { src = l0;  K = 64;  N = 64;  int f = frag-FL0;   kt = f/4;  nt = f%4; }
  else if (frag < FL2)   { src = l1;  K = 32;  N = 32;  kt = 0; nt = frag-FL1; }
  else                   { src = l2;  K = 16;  N = 16;  kt = 0; nt = 0; }
  const int n  = nt*16 + (lane & 15);
  const int k0 = kt*32 + (lane >> 4) * 8;
  u16* dst = ws + (size_t)frag * 512 + lane * 8;
  #pragma unroll
  for (int j = 0; j < 8; ++j) {
    const int k = k0 + j;
    const float v = (k < K && n < N) ? src[k * N + n] * sgn : 0.f;
    dst[j] = f2b(v);
  }
}

// ---------------- node pre-LN: f32[N][240] -> packed bf16[N][320] -------------
__global__ void ln_nodes(const float* __restrict__ nodef,
                         const float* __restrict__ w0, const float* __restrict__ b0,
                         const float* __restrict__ w1, const float* __restrict__ w2,
                         u16* __restrict__ nls, int N) {
  const int row  = blockIdx.x * 4 + (threadIdx.x >> 6);
  const int lane = threadIdx.x & 63;
  if (row >= N) return;
  const float* src = nodef + (size_t)row * 240;
  const float v0 = src[lane];
  const float v1 = src[lane + 64];
  const float v2 = src[lane + 128];
  const float v3 = (lane < 48) ? src[lane + 192] : 0.f;
  const bool lo = (lane < 32);
  float sm = v0, sq = v0*v0;
  float S1 = v1*v1 + (lo ? v2*v2 : 0.f);
  float S2 = (lo ? 0.f : v2*v2) + v3*v3;
  #pragma unroll
  for (int s = 32; s > 0; s >>= 1) {
    sm += __shfl_xor(sm, s, 64); sq += __shfl_xor(sq, s, 64);
    S1 += __shfl_xor(S1, s, 64); S2 += __shfl_xor(S2, s, 64);
  }
  const float mu  = sm * (1.f/64.f);
  const float i0  = rsqrtf(sq*(1.f/64.f) - mu*mu + 1e-8f);
  const float inv = rsqrtf(0.5f*(S1*(1.f/96.f) + S2*(1.f/80.f)) + 1e-8f);
  u16* dst = nls + (size_t)row * 320;
  dst[lane] = f2b((v0 - mu) * i0 * w0[lane] + b0[lane]);
  { const int u = lane;      const int c = u/3, j = u-3*c; dst[64 + 4*c + j]  = f2b(v1*inv*w1[c]); }
  if (lo) { const int u = lane+64; const int c = u/3, j = u-3*c; dst[64 + 4*c + j]  = f2b(v2*inv*w1[c]); }
  else    { const int u = lane-32; const int c = u/5, j = u-5*c; dst[192 + 8*c + j] = f2b(v2*inv*w2[c]); }
  if (lane < 48) { const int u = lane+32; const int c = u/5, j = u-5*c; dst[192 + 8*c + j] = f2b(v3*inv*w2[c]); }
  if (lane < 32) dst[64 + 4*lane + 3] = 0;
  if (lane < 48) { const int c = lane/3, j = lane-3*c; dst[192 + 8*c + 5 + j] = 0; }
}

// ------------------------------ main fused kernel -----------------------------
// LDS layout (bytes), total 39072 -> 4 blocks/CU:
//  0     m0  u16[16x472+8]=15120 | o0f f32[16][164]@0 ; g1s 3x[16x40]u16 @10496
//  15120 p1  u16[16x152+8]=4880  | op1f f32[16][52] ; ot f32[16][176] @15120
//  20000 n1  u16[16x152+8]=4880  | on1f
//  24880 p2  u16[16x56+8]=1808   | op2f
//  26688 n2  u16[16x56+8]=1808   | on2f
//  28496 scr f32[4][240]=3840    | gates u16[16][48]@28496 ; scs u16[16x72]@30032
//  32336 Dc  f32[16][44]=2816    ([0]=d00, [1+a*3+b]=l1, [12+a*5+b]=l2, 10/11/37..43 zeroed)
//  35152 g2s 5 x u16[16x24+8]=3920   (ends 39072)
__global__ __launch_bounds__(NT, 4)
void iel_mfma(const float* __restrict__ latents,
              const float* __restrict__ edgef,
              const float* __restrict__ wig,
              const float* __restrict__ ln_e_w0, const float* __restrict__ ln_e_b0,
              const float* __restrict__ ln_e_w1, const float* __restrict__ ln_e_w2,
              const float* __restrict__ lp_b0,
              const int* __restrict__ edge_index, const int* __restrict__ active_edges,
              const u16* __restrict__ ws, const u16* __restrict__ nls,
              float* __restrict__ out,
              int Etot, int A)
{
  __shared__ __align__(16) char SMEM[39072];
  u16*   m0   = (u16*)(SMEM);
  u16*   p1   = (u16*)(SMEM + 15120);
  u16*   n1   = (u16*)(SMEM + 20000);
  u16*   p2   = (u16*)(SMEM + 24880);
  u16*   n2   = (u16*)(SMEM + 26688);
  float* scr  = (float*)(SMEM + 28496);
  float* Dc   = (float*)(SMEM + 32336);
  u16*   g2s  = (u16*)(SMEM + 35152);
  float* o0f  = (float*)(SMEM);
  u16*   g1s  = (u16*)(SMEM + 10496);
  float* op1f = (float*)(SMEM + 15120);
  float* on1f = (float*)(SMEM + 20000);
  float* op2f = (float*)(SMEM + 24880);
  float* on2f = (float*)(SMEM + 26688);
  u16*   gates= (u16*)(SMEM + 28496);
  u16*   scs  = (u16*)(SMEM + 30032);
  float* ot   = (float*)(SMEM + 15120);   // phase-3 staging (post-A2 alias)

  const short8* WF = (const short8*)ws;
  const int t    = threadIdx.x;
  const int lane = t & 63;
  const int w    = t >> 6;
  const int eb0  = blockIdx.x * EB;
  const f32x4 Z4 = {0.f, 0.f, 0.f, 0.f};

  // ---- pad/tail clear: MFMA A-operands must never read NaN garbage ----------
  {
    const int r = t >> 4, c = t & 15;
    if (c < 8) {
      m0[r*472 + 464 + c] = 0;
      p1[r*152 + 144 + c] = 0;
      n1[r*152 + 144 + c] = 0;
      p2[r*56  + 48  + c] = 0;
      n2[r*56  + 48  + c] = 0;
      #pragma unroll
      for (int m = 0; m < 5; ++m) g2s[m*392 + r*24 + 16 + c] = 0;
    }
    if (t < 8) {
      m0[16*472 + t] = 0;
      p1[16*152 + t] = 0;
      n1[16*152 + t] = 0;
      p2[16*56  + t] = 0;
      n2[16*56  + t] = 0;
      #pragma unroll
      for (int m = 0; m < 5; ++m) g2s[m*392 + 384 + t] = 0;
    }
  }

  // ---- lane class: 0 = l1 triple (c=lane<32), 1 = l2 quint i=0..2, 2 = quint i=3..4
  const int cls = (lane < 32) ? 0 : ((lane < 48) ? 1 : 2);
  const int cc  = (cls == 0) ? lane : (lane & 15);
  const int dbase = (cls == 0) ? 1 : ((cls == 1) ? 12 : 27);
  const int dstr  = (cls == 0) ? 3 : 5;

  // ---- edge-LN staging scale factors (element-indexed) ----
  const int c1 = lane / 3;
  const bool q2lo = (lane < 32);
  const int c2 = q2lo ? (lane + 64) / 3 : (lane - 32) / 5;
  const int c3 = (lane < 48) ? (lane + 32) / 5 : 15;
  const float w0e = ln_e_w0[lane], b0e = ln_e_b0[lane];
  const float wAe = ln_e_w1[c1];
  const float wBe = q2lo ? ln_e_w1[c2] : ln_e_w2[c2];
  const float wCe = ln_e_w2[c3];

  float* swr = scr + w * 240;   // 176 floats used: [i] = element 64+i

  // ---- edge index prefetch (wave's 4 edges) ----
  int aev[4], ecv[4], env[4];
  #pragma unroll
  for (int it = 0; it < 4; ++it) {
    const int e = eb0 + (w<<2) + it;
    aev[it] = active_edges[(e < A) ? e : (A-1)];
  }
  #pragma unroll
  for (int it = 0; it < 4; ++it) {
    ecv[it] = edge_index[aev[it]];
    env[it] = edge_index[Etot + aev[it]];
  }

  // ---- stage compact Wigner D (stride 44); zero the gap/pad slots -----------
  #pragma unroll
  for (int it = 0; it < 4; ++it) {
    const int el = (w<<2) + it;
    const int e  = eb0 + el;
    const int eS = (e < A) ? e : (A-1);
    if (lane < 35) {
      int src, dst;
      if (lane == 0)      { src = 0; dst = 0; }
      else if (lane < 10) { const int a=(lane-1)/3, b=(lane-1)-3*((lane-1)/3); src=(1+a)*9+(1+b); dst=lane; }
      else                { const int a=(lane-10)/5, b=(lane-10)-5*((lane-10)/5); src=(4+a)*9+(4+b); dst=lane+2; }
      Dc[el*44 + dst] = wig[(size_t)eS*81 + src];
    } else if (lane < 44) {
      // zero Dc[10], Dc[11], Dc[37..43] — read (x coefficient padding) by the
      // class-uniform 5-term FMA; must be 0.0, never uninitialized (NaN*0=NaN)
      const int dst = (lane == 35) ? 10 : (lane == 36) ? 11 : lane;
      Dc[el*44 + dst] = 0.f;
    }
  }

  struct ER {
    u16 q0a, q0b, x4a, x4b;
    sv4 xa, xb;
    float e0, e1, e2, e3, l0, l1;
  };
  ER RA, RB;
  const int xoff = (cls == 0) ? (64 + 4*lane) : (192 + 8*cc);

  auto issue = [&](int it, ER& R) {
    const int e  = eb0 + (w<<2) + it;
    const int eS = (e < A) ? e : (A-1);
    const u16* nba = nls + (size_t)ecv[it]*320;
    const u16* nbb = nls + (size_t)env[it]*320;
    R.q0a = nba[lane]; R.q0b = nbb[lane];
    R.xa = ld4(nba + xoff); R.xb = ld4(nbb + xoff);
    R.x4a = (cls == 0) ? (u16)0 : nba[xoff + 4];
    R.x4b = (cls == 0) ? (u16)0 : nbb[xoff + 4];
    const float* ep = edgef + (size_t)eS*240;
    R.e0 = ep[lane]; R.e1 = ep[lane+64]; R.e2 = ep[lane+128];
    R.e3 = (lane < 48) ? ep[lane+192] : 0.f;
    const float* lr = latents + (size_t)aev[it]*128;
    R.l0 = lr[lane]; R.l1 = lr[64+lane];
  };

  auto process = [&](int it, ER& R) {
    const int el = (w<<2) + it;
    const float* DcE = Dc + el*44;
    const float d00 = DcE[0];
    float d[3][5];
    #pragma unroll
    for (int i = 0; i < 3; ++i)
      #pragma unroll
      for (int j = 0; j < 5; ++j)
        d[i][j] = DcE[dbase + i*dstr + j];

    // store bases (class-selected once per edge)
    u16* B0; u16* B1; u16* B2; int S0, S1, S2;
    if (cls == 0)      { B0 = n1 + el*152 + cc;      S0 = 48;  B1 = m0 + el*472 + 64 + cc; S1 = 112; B2 = p1 + el*152 + cc;      S2 = 48; }
    else if (cls == 1) { B0 = n2 + el*56  + cc;      S0 = 16;  B1 = n1 + el*152 + 32 + cc; S1 = 48;  B2 = m0 + el*472 + 96 + cc; S2 = 112; }
    else               { B0 = p1 + el*152 + 32 + cc; S0 = 48;  B1 = p2 + el*56  + cc;      S1 = 16;  B2 = m0;                    S2 = 0; }

    // node rows r=0 (ec) and r=2 (en)
    #pragma unroll
    for (int nr = 0; nr < 2; ++nr) {
      const int r = nr * 2;
      const u16 q0 = nr ? R.q0b : R.q0a;
      const sv4 xv = nr ? R.xb  : R.xa;
      const u16 x4u = nr ? R.x4b : R.x4a;
      const float x0 = b2f((u16)xv[0]), x1 = b2f((u16)xv[1]);
      const float x2 = b2f((u16)xv[2]), x3 = b2f((u16)xv[3]);
      const float x4 = b2f(x4u);
      m0[el*472 + r*112 + lane] = f2b(b2f(q0) * d00);
      float s0v = d[0][0]*x0 + d[0][1]*x1 + d[0][2]*x2 + d[0][3]*x3 + d[0][4]*x4;
      float s1v = d[1][0]*x0 + d[1][1]*x1 + d[1][2]*x2 + d[1][3]*x3 + d[1][4]*x4;
      float s2v = d[2][0]*x0 + d[2][1]*x1 + d[2][2]*x2 + d[2][3]*x3 + d[2][4]*x4;
      B0[r*S0] = f2b(s0v);
      B1[r*S1] = f2b(s1v);
      if (lane < 48) B2[r*S2] = f2b(s2v);
    }

    // edge row r=1: full LN + rotation
    {
      const float v0 = R.e0, v1 = R.e1, v2 = R.e2, v3 = R.e3;
      float sm = v0, sq = v0*v0;
      float S1r = v1*v1 + (q2lo ? v2*v2 : 0.f);
      float S2r = (q2lo ? 0.f : v2*v2) + v3*v3;
      #pragma unroll
      for (int s = 32; s > 0; s >>= 1) {
        sm += __shfl_xor(sm, s, 64);  sq += __shfl_xor(sq, s, 64);
        S1r += __shfl_xor(S1r, s, 64); S2r += __shfl_xor(S2r, s, 64);
      }
      const float mu = sm * (1.f/64.f);
      const float i0 = rsqrtf(sq*(1.f/64.f) - mu*mu + 1e-8f);
      const float iv = rsqrtf(0.5f*(S1r*(1.f/96.f) + S2r*(1.f/80.f)) + 1e-8f);
      swr[lane]      = v1 * iv * wAe;
      swr[64 + lane] = v2 * iv * wBe;
      if (lane < 48) swr[128 + lane] = v3 * iv * wCe;
      asm volatile("s_waitcnt lgkmcnt(0)" ::: "memory");
      m0[el*472 + 112 + lane] = f2b(((v0 - mu)*i0*w0e + b0e) * d00);
      const float* sb = (cls == 0) ? (swr + 3*cc) : (swr + 96 + 5*cc);
      const float x0 = sb[0], x1 = sb[1], x2 = sb[2];
      const float x3 = (cls == 0) ? 0.f : sb[3];
      const float x4 = (cls == 0) ? 0.f : sb[4];
      float s0v = d[0][0]*x0 + d[0][1]*x1 + d[0][2]*x2 + d[0][3]*x3 + d[0][4]*x4;
      float s1v = d[1][0]*x0 + d[1][1]*x1 + d[1][2]*x2 + d[1][3]*x3 + d[1][4]*x4;
      float s2v = d[2][0]*x0 + d[2][1]*x1 + d[2][2]*x2 + d[2][3]*x3 + d[2][4]*x4;
      B0[S0] = f2b(s0v);
      B1[S1] = f2b(s1v);
      if (lane < 48) B2[S2] = f2b(s2v);
    }
    m0[el*472 + 336 + lane] = f2b(R.l0);
    m0[el*472 + 400 + lane] = f2b(R.l1);
  };

  // ---- Phase 1 software pipeline ----
  issue(0, RA);
  issue(1, RB); process(0, RA);
  issue(2, RA); process(1, RB);
  issue(3, RB); process(2, RA);
  process(3, RB);
  __syncthreads();  // B2: features + Dc ready

  // ---- Phase 2a: o0 = m0 @ so2_w0 (10 N-tiles over 4 waves) ----
  f32x4 acc2a[3] = {Z4, Z4, Z4};
  {
    const u16* abase = m0 + (lane & 15)*472 + (lane >> 4)*8;
    #pragma unroll
    for (int kt = 0; kt < 15; ++kt) {
      const short8 a = *reinterpret_cast<const short8*>(abase + kt*32);
      #pragma unroll
      for (int i = 0; i < 3; ++i) {
        const int nt = w + 4*i;
        if (nt < 10)
          acc2a[i] = MFMA(a, WF[(size_t)(FW0 + kt*10 + nt)*64 + lane], acc2a[i]);
      }
    }
  }
  // ---- Phase 2b/2c (reads p1/n1/p2/n2) ----
  f32x4 acc2b[2] = {Z4, Z4};
  f32x4 acc2c = Z4;
  {
    const u16* pbase = p1 + (lane & 15)*152 + (lane >> 4)*8;
    const u16* nbase = n1 + (lane & 15)*152 + (lane >> 4)*8;
    #pragma unroll
    for (int kt = 0; kt < 5; ++kt) {
      const short8 pa = *reinterpret_cast<const short8*>(pbase + kt*32);
      const short8 na = *reinterpret_cast<const short8*>(nbase + kt*32);
      #pragma unroll
      for (int i = 0; i < 2; ++i) {
        const int tau = w + 4*i;
        if (tau < 6) {
          const int isOn = (tau >= 3) ? 1 : 0;
          const int nt2 = tau - 3*isOn;
          acc2b[i] = MFMA(pa, WF[(size_t)((isOn?FW1I:FW1R)  + kt*3 + nt2)*64 + lane], acc2b[i]);
          acc2b[i] = MFMA(na, WF[(size_t)((isOn?FW1R:FW1IN) + kt*3 + nt2)*64 + lane], acc2b[i]);
        }
      }
    }
    if (w >= 2) {
      const u16* pb2 = p2 + (lane & 15)*56 + (lane >> 4)*8;
      const u16* nb2 = n2 + (lane & 15)*56 + (lane >> 4)*8;
      const int isOn2 = (w == 3);
      #pragma unroll
      for (int kt = 0; kt < 2; ++kt) {
        const short8 pa = *reinterpret_cast<const short8*>(pb2 + kt*32);
        const short8 na = *reinterpret_cast<const short8*>(nb2 + kt*32);
        acc2c = MFMA(pa, WF[(size_t)((isOn2?FW2I:FW2R)  + kt)*64 + lane], acc2c);
        acc2c = MFMA(na, WF[(size_t)((isOn2?FW2R:FW2IN) + kt)*64 + lane], acc2c);
      }
    }
  }
  __syncthreads();  // B3: all feature reads done

  // o0 write (aliases m0)
  {
    #pragma unroll
    for (int i = 0; i < 3; ++i) {
      const int nt = w + 4*i;
      if (nt < 10) {
        const int col = nt*16 + (lane & 15);
        const int r0  = (lane >> 4)*4;
        #pragma unroll
        for (int j = 0; j < 4; ++j)
          o0f[(r0+j)*164 + col] = acc2a[i][j] * 0.046423835f;   // 1/sqrt(464)
      }
    }
  }
  __syncthreads();  // B4: o0 ready

  // op1/on1/op2/on2 writes + A1 (silu/gates)
  {
    #pragma unroll
    for (int i = 0; i < 2; ++i) {
      const int tau = w + 4*i;
      if (tau < 6) {
        const int isOn = (tau >= 3) ? 1 : 0;
        const int nt2 = tau - 3*isOn;
        float* dst = isOn ? on1f : op1f;
        const int col = nt2*16 + (lane & 15);
        const int r0  = (lane >> 4)*4;
        #pragma unroll
        for (int j = 0; j < 4; ++j)
          dst[(r0+j)*52 + col] = acc2b[i][j] * (1.f/12.f);
      }
    }
    if (w >= 2) {
      float* dst = (w == 3) ? on2f : op2f;
      const int r0 = (lane >> 4)*4;
      #pragma unroll
      for (int j = 0; j < 4; ++j)
        dst[(r0+j)*20 + (lane & 15)] = acc2c[j] * 0.14433757f;  // 1/sqrt(48)
    }
  }
  {
    const int e = t >> 4, l16 = t & 15;
    const float d0 = Dc[e*44];
    #pragma unroll
    for (int k = 0; k < 7; ++k) {
      const int p = l16 + 16*k;
      const float x = o0f[e*164 + p] * d0;
      const float sg = 1.f/(1.f + __expf(-x));
      if (p < 64) scs[e*72 + p] = f2b(x * sg);
      else        gates[e*48 + (p - 64)] = f2b(sg);
    }
  }
  __syncthreads();  // B5

  // A2: rotate-back + gate -> g1/g2 bf16 staging
  {
    const int e = t >> 4, l16 = t & 15;
    const float* DcE = Dc + e*44;
    #pragma unroll
    for (int k = 0; k < 6; ++k) {
      const int item = l16 + 16*k;            // 0..95
      const int c = item/3, m = item - 3*c;
      const float val = DcE[1 + m]     * on1f[e*52 + c]
                      + DcE[1 + 3 + m] * o0f[e*164 + 112 + c]
                      + DcE[1 + 6 + m] * op1f[e*52 + c];
      const float g = b2f(gates[e*48 + c]);
      g1s[m*640 + e*40 + c] = f2b(val * g);
    }
    const int c = l16;
    const float f0 = on2f[e*20 + c];
    const float f1 = on1f[e*52 + 32 + c];
    const float f2c = o0f[e*164 + 144 + c];
    const float f3 = op1f[e*52 + 32 + c];
    const float f4 = op2f[e*20 + c];
    const float gg = b2f(gates[e*48 + 32 + c]);
    #pragma unroll
    for (int m = 0; m < 5; ++m) {
      const float val = DcE[12 + m]*f0 + DcE[12 + 5 + m]*f1 + DcE[12 + 10 + m]*f2c
                      + DcE[12 + 15 + m]*f3 + DcE[12 + 20 + m]*f4;
      g2s[m*392 + e*24 + c] = f2b(val * gg);
    }
  }
  __syncthreads();  // B6

  // ---- Phase 3: final matmuls; y0 direct, y1/y2 staged to ot then coalesced --
  for (int tau = w; tau < 15; tau += 4) {
    const int col16 = lane & 15;
    const int r0 = (lane >> 4)*4;
    if (tau < 4) {            // y0: sc[16x64] @ lp_w0 -> direct (line-aligned)
      const int ntt = tau;
      f32x4 a0 = Z4;
      #pragma unroll
      for (int kt = 0; kt < 2; ++kt) {
        const short8 a = *reinterpret_cast<const short8*>(
            scs + (lane & 15)*72 + kt*32 + (lane >> 4)*8);
        a0 = MFMA(a, WF[(size_t)(FL0 + kt*4 + ntt)*64 + lane], a0);
      }
      const int col = ntt*16 + col16;
      const float bias = lp_b0[col];
      #pragma unroll
      for (int j = 0; j < 4; ++j) {
        const int er = eb0 + r0 + j;
        if (er < A) out[(size_t)er*240 + col] = a0[j]*0.125f + bias;
      }
    } else if (tau < 10) {    // y1 -> ot cols [0,96)
      const int u = tau - 4, m = u >> 1, ntt = u & 1;
      const short8 a = *reinterpret_cast<const short8*>(
          g1s + m*640 + (lane & 15)*40 + (lane >> 4)*8);
      f32x4 a0 = Z4;
      a0 = MFMA(a, WF[(size_t)(FL1 + ntt)*64 + lane], a0);
      const int oc = (ntt*16 + col16)*3 + m;
      #pragma unroll
      for (int j = 0; j < 4; ++j)
        ot[(r0+j)*176 + oc] = a0[j]*0.17677670f;   // 1/sqrt(32)
    } else {                  // y2 -> ot cols [96,176)
      const int m = tau - 10;
      const short8 a = *reinterpret_cast<const short8*>(
          g2s + m*392 + (lane & 15)*24 + (lane >> 4)*8);
      f32x4 a0 = Z4;
      a0 = MFMA(a, WF[(size_t)FL2*64 + lane], a0);
      const int oc = 96 + col16*5 + m;
      #pragma unroll
      for (int j = 0; j < 4; ++j)
        ot[(r0+j)*176 + oc] = a0[j]*0.25f;         // 1/sqrt(16)
    }
  }
  __syncthreads();  // B7: ot complete

  // coalesced copy-out of cols 64..239 (44 float4 per row)
  for (int idx = t; idx < 16*44; idx += NT) {
    const int row = idx / 44, seg = idx - row*44;
    const int er = eb0 + row;
    if (er < A) {
      const f32x4 v = *reinterpret_cast<const f32x4*>(ot + row*176 + seg*4);
      *reinterpret_cast<f32x4*>(out + (size_t)er*240 + 64 + seg*4) = v;
    }
  }
}

extern "C" void kernel_launch(void* const* d_in, const int* in_sizes, int n_in,
                              void* d_out, int out_size, void* d_ws, size_t ws_size,
                              hipStream_t stream) {
  const float* latents  = (const float*)d_in[0];
  const float* nodef    = (const float*)d_in[1];
  const float* edgef    = (const float*)d_in[2];
  const float* wig      = (const float*)d_in[4];
  const float* ln_n_w0  = (const float*)d_in[5];
  const float* ln_n_b0  = (const float*)d_in[6];
  const float* ln_n_w1  = (const float*)d_in[7];
  const float* ln_n_w2  = (const float*)d_in[8];
  const float* ln_e_w0  = (const float*)d_in[9];
  const float* ln_e_b0  = (const float*)d_in[10];
  const float* ln_e_w1  = (const float*)d_in[11];
  const float* ln_e_w2  = (const float*)d_in[12];
  const float* so2_w0   = (const float*)d_in[13];
  const float* so2_w1r  = (const float*)d_in[14];
  const float* so2_w1i  = (const float*)d_in[15];
  const float* so2_w2r  = (const float*)d_in[16];
  const float* so2_w2i  = (const float*)d_in[17];
  const float* lp_w0    = (const float*)d_in[18];
  const float* lp_b0    = (const float*)d_in[19];
  const float* lp_w1    = (const float*)d_in[20];
  const float* lp_w2    = (const float*)d_in[21];
  const int*   edge_index   = (const int*)d_in[22];
  const int*   active_edges = (const int*)d_in[23];

  const int Etot = in_sizes[2] / 240;
  const int N    = in_sizes[1] / 240;
  const int A    = in_sizes[23];

  u16* ws  = (u16*)d_ws;                 // WF table: NFRAG*1024 B
  u16* nls = ws + WS_NLS_OFF;            // node-LN table: N*640 B

  const int pthreads = NFRAG * 64;
  hipLaunchKernelGGL(prep_w, dim3((pthreads + 255) / 256), dim3(256), 0, stream,
                     so2_w0, so2_w1r, so2_w1i, so2_w2r, so2_w2i,
                     lp_w0, lp_w1, lp_w2, ws);

  hipLaunchKernelGGL(ln_nodes, dim3((N + 3) / 4), dim3(256), 0, stream,
                     nodef, ln_n_w0, ln_n_b0, ln_n_w1, ln_n_w2, nls, N);

  const int grid = (A + EB - 1) / EB;
  hipLaunchKernelGGL(iel_mfma, dim3(grid), dim3(NT), 0, stream,
                     latents, edgef, wig,
                     ln_e_w0, ln_e_b0, ln_e_w1, ln_e_w2,
                     lp_b0, edge_index, active_edges, ws, nls,
                     (float*)d_out, Etot, A);
}